// Round 8
// baseline (417.048 us; speedup 1.0000x reference)
//
#include <hip/hip_runtime.h>
#include <hip/hip_bf16.h>
#include <stdint.h>

// Problem constants
#define SEQ   2048
#define NHEAD 16
#define DHEAD 64
#define NROWS 4096      // BSZ*SEQ
#define MDIM  2048      // model dim
#define QKVN  6144
#define EPSF  1e-5f
#define LAMBDA_INIT 0.7999593627581f
#define QSCALE 0.18033688011112042f   // dh^-0.5 * log2(e): flash softmax runs in exp2 domain

typedef unsigned short u16;
typedef __attribute__((ext_vector_type(8))) short bf16x8;   // 8 bf16 = 4 VGPRs
typedef __attribute__((ext_vector_type(4))) float f32x4;
typedef __attribute__((ext_vector_type(4))) unsigned short u16x4;

// async global->LDS, 16B/lane: data lands at LDS base + lane*16 (wave-uniform base).
#define GLD_LDS16(g, l) \
  __builtin_amdgcn_global_load_lds((const __attribute__((address_space(1))) void*)(g), \
                                   (__attribute__((address_space(3))) void*)(l), 16, 0, 0)

__device__ __forceinline__ u16 f2bf(float f) {
  union { float f; uint32_t u; } v; v.f = f;
  return (u16)((v.u + 0x7fffu + ((v.u >> 16) & 1u)) >> 16);   // RNE
}
__device__ __forceinline__ float bf2f(uint32_t s) {
  union { uint32_t u; float f; } v; v.u = s << 16; return v.f;
}
// packed fp32x2 -> bf16x2 (gfx950 v_cvt_pk_bf16_f32 via HIP API), RNE
__device__ __forceinline__ uint32_t pk2(float a, float b) {
  __hip_bfloat162 h = __float22bfloat162_rn(make_float2(a, b));
  union { __hip_bfloat162 h; uint32_t u; } v; v.h = h; return v.u;
}

// ---------------- unified cast: x, 4 weights, cos/sin float2 table ----------
__global__ __launch_bounds__(256) void k_castall(const float4* __restrict__ x,
                                                 const float4* __restrict__ wq,
                                                 const float4* __restrict__ wk,
                                                 const float4* __restrict__ wv,
                                                 const float4* __restrict__ wo,
                                                 const float4* __restrict__ rc,
                                                 const float4* __restrict__ rsn,
                                                 u16* __restrict__ Xbf,
                                                 u16* __restrict__ Wqkv,
                                                 u16* __restrict__ Wob,
                                                 float4* __restrict__ CS) {
  int bid = blockIdx.x, t = threadIdx.x;
  if (bid < 8192) {                       // x: 2.097M float4
    int i = bid * 256 + t;
    float4 f = x[i];
    u16x4 o; o.x = f2bf(f.x); o.y = f2bf(f.y); o.z = f2bf(f.z); o.w = f2bf(f.w);
    *(u16x4*)(Xbf + (size_t)i * 4) = o;
  } else if (bid < 24576) {               // 4 weights x 1.048M float4
    int widx = (bid - 8192) >> 12;
    int i = ((bid - 8192) & 4095) * 256 + t;
    const float4* s = widx == 0 ? wq : widx == 1 ? wk : widx == 2 ? wv : wo;
    u16* d = widx < 3 ? (Wqkv + (size_t)widx * 4194304) : Wob;
    float4 f = s[i];
    u16x4 o; o.x = f2bf(f.x); o.y = f2bf(f.y); o.z = f2bf(f.z); o.w = f2bf(f.w);
    *(u16x4*)(d + (size_t)i * 4) = o;
  } else {                                // CS[s*32+i] = (cos, sin) float2; 16384 f4
    int j = (bid - 24576) * 256 + t;
    float4 c = rc[j], s = rsn[j];
    CS[(size_t)j * 2]     = make_float4(c.x, s.x, c.y, s.y);
    CS[(size_t)j * 2 + 1] = make_float4(c.z, s.z, c.w, s.w);
  }
}

// ---------------- GEMM1, 256x256 8-phase counted-vmcnt ----------------------
// R8: gate flight-time fix. Unit liveness: slot0 fully read across P1-P3
// (wave-split rows), B0 dead after P2, A0 after P3; slot1 mirrored P5-P7.
// OLD staging put B-hi only 2 phases before its gate (P2->P4gate, P6->P8gate)
// = ~550cy < HBM 900cy -> every gate stalled on B-hi. NEW placement stages
// B-hi with B-lo right after death (P3: B0 lo+hi; P7: B1 lo+hi), giving every
// load >=3 phases of flight. Gates relax vmcnt(4)->vmcnt(6):
//   P4-end outstanding [pP7x4,pP8x2,P1x2,P3x4,P4x2]=14 -> vmcnt(6) retires
//   exactly P5's needs {B1lo,hi@pP7, A1lo@pP8, A1hi@P1}; P8-end symmetric.
#define PH_BAR asm volatile("s_barrier" ::: "memory")
#define VMW8   asm volatile("s_waitcnt vmcnt(8)" ::: "memory")
#define VMW6   asm volatile("s_waitcnt vmcnt(6)" ::: "memory")
#define VMW0   asm volatile("s_waitcnt vmcnt(0)" ::: "memory")

// stage one half-tile (128 rows x 64 cols bf16 = 2 x 8KB block-wide loads)
#define STAGEH(Gb, dst, r0, kt) do { \
  GLD_LDS16((Gb) + (size_t)(r0) * MDIM + (kt) * 64,        (dst) + (r0) * 64 + wofs); \
  GLD_LDS16((Gb) + (size_t)((r0) + 64) * MDIM + (kt) * 64, (dst) + ((r0) + 64) * 64 + wofs); \
} while (0)

#define RDA(base, mi0) do { \
  _Pragma("unroll") for (int mi = 0; mi < 4; mi++) { \
    const int ar = wr * 128 + ((mi0) + mi) * 16 + n; \
    _Pragma("unroll") for (int kk = 0; kk < 2; kk++) \
      af[mi][kk] = *(const bf16x8*)((base) + ((size_t)ar * 8 + (((kk * 4 + g) ^ ar) & 7)) * 8); \
  } } while (0)

#define RDB(dst, base, ni0) do { \
  _Pragma("unroll") for (int nj = 0; nj < 2; nj++) { \
    const int br = wc * 64 + ((ni0) + nj) * 16 + n; \
    _Pragma("unroll") for (int kk = 0; kk < 2; kk++) \
      dst[nj][kk] = *(const bf16x8*)((base) + ((size_t)br * 8 + (((kk * 4 + g) ^ br) & 7)) * 8); \
  } } while (0)

#define MMQ(mi0, ni0, bf) do { \
  __builtin_amdgcn_s_setprio(1); \
  _Pragma("unroll") for (int mi = 0; mi < 4; mi++) \
    _Pragma("unroll") for (int nj = 0; nj < 2; nj++) \
      _Pragma("unroll") for (int kk = 0; kk < 2; kk++) \
        acc[(mi0) + mi][(ni0) + nj] = __builtin_amdgcn_mfma_f32_16x16x32_bf16( \
            af[mi][kk], bf[nj][kk], acc[(mi0) + mi][(ni0) + nj], 0, 0, 0); \
  __builtin_amdgcn_s_setprio(0); \
} while (0)

__global__ __launch_bounds__(512, 2) void k_gemm_qkv(const u16* __restrict__ A,
                                                     const u16* __restrict__ B,
                                                     const float2* __restrict__ CS2,
                                                     u16* __restrict__ Qb,
                                                     u16* __restrict__ Kb,
                                                     u16* __restrict__ Vt) {
  __shared__ __align__(16) u16 As[2][16384];   // [slot][256 rows][64 cols]
  __shared__ __align__(16) u16 Bs[2][16384];
  const int t = threadIdx.x, w = t >> 6, l = t & 63, n = l & 15, g = (l >> 4) & 3;
  const int wr = w >> 2, wc = w & 3;
  // bijective XCD swizzle: 384 blocks, 48 per XCD, contiguous tile chunks
  const int bid = blockIdx.x;
  const int swz = (bid & 7) * 48 + (bid >> 3);
  const int by = swz / 24, bx = swz - by * 24;
  const int m0 = by * 256, n0 = bx * 256;

  // staging: thread t covers (row = t>>3, chunk cc = t&7); source chunk is
  // pre-swizzled (cc ^ row) so LDS stays linear for global_load_lds.
  const int srow = t >> 3, scg = ((t & 7) ^ srow) & 7;
  const u16* Ag = A + (size_t)(m0 + srow) * MDIM + scg * 8;
  const u16* Bg = B + (size_t)(n0 + srow) * MDIM + scg * 8;
  const int wofs = w * 512;                    // per-wave LDS dest (u16)

  f32x4 acc[8][4];
  #pragma unroll
  for (int i = 0; i < 8; i++)
    #pragma unroll
    for (int j = 0; j < 4; j++) acc[i][j] = (f32x4){0.f, 0.f, 0.f, 0.f};
  bf16x8 af[4][2], b0[2][2], b1[2][2];

  u16* const A0 = As[0]; u16* const A1 = As[1];
  u16* const B0 = Bs[0]; u16* const B1 = Bs[1];

  // prologue: tiles 0 (slot0) then 1 (slot1); tile0 = oldest 8 loads
  STAGEH(Ag, A0, 0, 0);  STAGEH(Ag, A0, 128, 0);
  STAGEH(Bg, B0, 0, 0);  STAGEH(Bg, B0, 128, 0);
  STAGEH(Ag, A1, 0, 1);  STAGEH(Ag, A1, 128, 1);
  STAGEH(Bg, B1, 0, 1);  STAGEH(Bg, B1, 128, 1);
  VMW8; PH_BAR;

  #pragma unroll 1
  for (int i = 0; i < 16; ++i) {
    const int t1 = 2 * i + 1, t2 = 2 * i + 2, t3 = 2 * i + 3;
    // ---- P1: reads slot0 A[qm0]+B[qn0]; stage A1-hi(t1)
    RDA(A0, 0); RDB(b0, B0, 0);
    if (i >= 1) STAGEH(Ag, A1, 128, t1);
    PH_BAR; MMQ(0, 0, b0); PH_BAR;
    // ---- P2: reads B[qn1]; (no staging — B1-hi moved to P7 for flight time)
    RDB(b1, B0, 2);
    PH_BAR; MMQ(0, 2, b1); PH_BAR;
    // ---- P3: reads A[qm1]; stage B0-lo(t2) + B0-hi(t2) (B0 dead after P2)
    RDA(A0, 4);
    if (i < 15) { STAGEH(Bg, B0, 0, t2); STAGEH(Bg, B0, 128, t2); }
    PH_BAR; MMQ(4, 2, b1); PH_BAR;
    // ---- P4: regs only; stage A0-lo(t2); gate vmcnt(6)
    if (i < 15) STAGEH(Ag, A0, 0, t2);
    PH_BAR; MMQ(4, 0, b0);
    if (i < 15) { VMW6; } else { VMW0; }
    PH_BAR;
    // ---- P5: reads slot1 A[qm0]+B[qn0]; stage A0-hi(t2)
    RDA(A1, 0); RDB(b0, B1, 0);
    if (i < 15) STAGEH(Ag, A0, 128, t2);
    PH_BAR; MMQ(0, 0, b0); PH_BAR;
    // ---- P6: reads B[qn1]; (no staging — B0-hi moved to P3)
    RDB(b1, B1, 2);
    PH_BAR; MMQ(0, 2, b1); PH_BAR;
    // ---- P7: reads A[qm1]; stage B1-lo(t3) + B1-hi(t3) (B1 dead after P6)
    RDA(A1, 4);
    if (i < 15) { STAGEH(Bg, B1, 0, t3); STAGEH(Bg, B1, 128, t3); }
    PH_BAR; MMQ(4, 2, b1); PH_BAR;
    // ---- P8: stage A1-lo(t3); gate vmcnt(6)
    if (i < 15) STAGEH(Ag, A1, 0, t3);
    PH_BAR; MMQ(4, 0, b0);
    if (i < 15) VMW6;
    PH_BAR;
  }

  // ---- epilogue: fused RoPE (Q/K) or direct-transposed V (Q=bx0..7,
  // K=8..15, V=16..23)
  if (bx < 16) {                                  // Q (bx<8) or K block
    const float scale = bx < 8 ? QSCALE : 1.0f;
    u16* outb = bx < 8 ? Qb : Kb;
    const float sgn = (n & 1) ? 1.0f : -1.0f;
    #pragma unroll
    for (int mi = 0; mi < 8; mi++)
      #pragma unroll
      for (int r = 0; r < 4; r++) {
        const int row = m0 + wr * 128 + mi * 16 + g * 4 + r;
        const int s = row & (SEQ - 1);
        #pragma unroll
        for (int ni = 0; ni < 4; ni++) {
          const int cl = wc * 64 + ni * 16 + n;
          float val = acc[mi][ni][r];
          float par = __shfl_xor(val, 1);
          float2 cs = CS2[(size_t)s * 32 + ((cl >> 1) & 31)];
          float o = (val * cs.x + sgn * par * cs.y) * scale;
          const int col = n0 + cl;
          const int inst = (row >> 11) * 32 + ((col >> 6) & 31);
          outb[((size_t)inst * SEQ + s) * 64 + (col & 63)] = f2bf(o);
        }
      }
  } else {                                        // V block -> tiled Vt direct
    // Vt[((bh*64 + s>>5)*128 + dv)*32 + (s&31)] = V[b*SEQ+s][h*128+dv]
    // r=0..3 -> s consecutive (s0 % 4 == 0): one aligned 8B u16x4 store.
    const int vb = (bx - 16) * 256;
    #pragma unroll
    for (int mi = 0; mi < 8; mi++) {
      const int row0 = m0 + wr * 128 + mi * 16 + g * 4;
      const int s0 = row0 & (SEQ - 1);
      const int bb = row0 >> 11;
      #pragma unroll
      for (int ni = 0; ni < 4; ni++) {
        const int vcol = vb + wc * 64 + ni * 16 + n;
        const int hh = vcol >> 7, dv = vcol & 127;
        const int bh2 = bb * 16 + hh;
        u16x4 pk;
        pk.x = f2bf(acc[mi][ni][0]);
        pk.y = f2bf(acc[mi][ni][1]);
        pk.z = f2bf(acc[mi][ni][2]);
        pk.w = f2bf(acc[mi][ni][3]);
        *(u16x4*)(Vt + ((size_t)(bh2 * 64 + (s0 >> 5)) * 128 + dv) * 32 + (s0 & 31)) = pk;
      }
    }
  }
}

// ---------------- generic BT-GEMM (GEMM2, fp32 out) ----------------
template<int BF16OUT>
__global__ __launch_bounds__(256) void k_gemm_bt(const u16* __restrict__ A,
                                                 const u16* __restrict__ B,
                                                 void* __restrict__ Cp,
                                                 int M, int N, int K) {
  __shared__ __align__(16) u16 As2[128 * 64];
  __shared__ __align__(16) u16 Bs2[128 * 64];
  const int t = threadIdx.x, w = t >> 6, l = t & 63, n = l & 15, g = l >> 4;
  const int m0 = blockIdx.y * 128, n0 = blockIdx.x * 128;
  const int wm = (w >> 1) * 64, wn = (w & 1) * 64;
  f32x4 acc[4][4];
  #pragma unroll
  for (int i = 0; i < 4; i++)
    #pragma unroll
    for (int j = 0; j < 4; j++) acc[i][j] = (f32x4){0.f, 0.f, 0.f, 0.f};

  for (int kt = 0; kt < K; kt += 64) {
    #pragma unroll
    for (int p = 0; p < 4; ++p) {
      int id = p * 256 + t;
      int row = id >> 3, cc = id & 7, ccg = (cc ^ row) & 7;
      GLD_LDS16(A + (size_t)(m0 + row) * K + kt + ccg * 8, As2 + (size_t)(p * 256 + w * 64) * 8);
      GLD_LDS16(B + (size_t)(n0 + row) * K + kt + ccg * 8, Bs2 + (size_t)(p * 256 + w * 64) * 8);
    }
    __syncthreads();
    bf16x8 af[4][2], bfr[4][2];
    #pragma unroll
    for (int mi = 0; mi < 4; mi++) {
      int row = wm + mi * 16 + n;
      #pragma unroll
      for (int c = 0; c < 2; c++)
        af[mi][c] = *(const bf16x8*)(As2 + ((size_t)row * 8 + (((c * 4 + g) ^ row) & 7)) * 8);
    }
    #pragma unroll
    for (int ni = 0; ni < 4; ni++) {
      int row = wn + ni * 16 + n;
      #pragma unroll
      for (int c = 0; c < 2; c++)
        bfr[ni][c] = *(const bf16x8*)(Bs2 + ((size_t)row * 8 + (((c * 4 + g) ^ row) & 7)) * 8);
    }
    #pragma unroll
    for (int mi = 0; mi < 4; mi++)
      #pragma unroll
      for (int ni = 0; ni < 4; ni++)
        #pragma unroll
        for (int c = 0; c < 2; c++)
          acc[mi][ni] = __builtin_amdgcn_mfma_f32_16x16x32_bf16(af[mi][c], bfr[ni][c], acc[mi][ni], 0, 0, 0);
    __syncthreads();
  }
  #pragma unroll
  for (int mi = 0; mi < 4; mi++)
    #pragma unroll
    for (int ni = 0; ni < 4; ni++)
      #pragma unroll
      for (int r = 0; r < 4; r++) {
        int row = m0 + wm + mi * 16 + g * 4 + r;
        int col = n0 + wn + ni * 16 + n;
        if (BF16OUT) ((u16*)Cp)[(size_t)row * N + col] = f2bf(acc[mi][ni][r]);
        else         ((float*)Cp)[(size_t)row * N + col] = acc[mi][ni][r];
      }
}

// ---------------- flash attention v11: KVBLK=64 staging/barrier granularity.
// (R6-measured WIN; unchanged)
__global__ __launch_bounds__(256, 2) void k_flash(const u16* __restrict__ Q,
                                                  const u16* __restrict__ K,
                                                  const u16* __restrict__ V,
                                                  u16* __restrict__ PA, u16* __restrict__ PB,
                                                  float* __restrict__ LA, float* __restrict__ LB) {
  __shared__ __align__(16) u16 Ks[2][64 * 64];    // 8KB/buf: two 32x64 sub-tiles
  __shared__ __align__(16) u16 Vs[2][128 * 64];   // 16KB/buf: two [128dv][32key] sub-tiles
  __shared__ __align__(16) u16 Ps[4][32 * 32];
  const int t = threadIdx.x, w = t >> 6, l = t & 63, n = l & 15, g = l >> 4;
  const int gb = blockIdx.x;
  const int xcd = gb & 7, qq = gb >> 3, j = qq & 15, ihi = qq >> 4;
  const int inst = ihi * 8 + xcd;
  const int b = inst >> 5, rh = inst & 31, h = rh >> 1, bh = b * 16 + h;
  const u16* Qp = Q + (size_t)inst * SEQ * 64;
  const u16* Kp = K + (size_t)inst * SEQ * 64;
  const u16* Vp = V + (size_t)bh * 262144;
  u16* Pw = Ps[w];

  #pragma unroll
  for (int ch = 0; ch < 2; ch++) {
    const int tile = ch ? j : (15 - j);
    const int k0 = ch ? (2 * j + 2) : 0;          // 32-key units (always even)
    const int k1 = ch ? (4 * j + 4) : (32 - 2 * j);
    const int T0 = k0 >> 1, T1 = k1 >> 1;         // 64-key tiles
    const int rw = tile * 128 + w * 32;
    u16* Od = ch ? PB : PA;
    float* Ld = ch ? LB : LA;

    bf16x8 qf[2][2];
    #pragma unroll
    for (int q2 = 0; q2 < 2; q2++)
      #pragma unroll
      for (int c = 0; c < 2; c++)
        qf[q2][c] = *(const bf16x8*)(Qp + (size_t)(rw + q2 * 16 + n) * 64 + c * 32 + g * 8);

    f32x4 o_acc[2][8];
    #pragma unroll
    for (int q2 = 0; q2 < 2; q2++)
      #pragma unroll
      for (int nb = 0; nb < 8; nb++) o_acc[q2][nb] = (f32x4){0.f, 0.f, 0.f, 0.f};
    float lsum[2] = {0.f, 0.f};

    __syncthreads();
    {   // stage 64-key tile T0 -> buffer 0
      int row = t >> 3, cc = t & 7, ccg = cc ^ (row & 7);
      GLD_LDS16(Kp + (size_t)(T0 * 64 + row) * 64 + ccg * 8,      Ks[0] + (size_t)w * 512);
      GLD_LDS16(Kp + (size_t)(T0 * 64 + 32 + row) * 64 + ccg * 8, Ks[0] + 2048 + (size_t)w * 512);
      #pragma unroll
      for (int sub = 0; sub < 2; sub++)
        #pragma unroll
        for (int p = 0; p < 2; p++) {
          int id = p * 256 + t, vr = id >> 2, vc = id & 3;
          int vcg = vc ^ (vr & 3) ^ ((vr >> 2) & 3);
          GLD_LDS16(Vp + (size_t)(T0 * 2 + sub) * 4096 + vr * 32 + vcg * 8,
                    Vs[0] + sub * 4096 + (size_t)(p * 256 + w * 64) * 8);
        }
    }

    for (int T = T0; T < T1; ++T) {
      const int par = (T - T0) & 1;
      __syncthreads();
      if (T + 1 < T1) {
        int row = t >> 3, cc = t & 7, ccg = cc ^ (row & 7);
        GLD_LDS16(Kp + (size_t)((T + 1) * 64 + row) * 64 + ccg * 8,
                  Ks[par ^ 1] + (size_t)w * 512);
        GLD_LDS16(Kp + (size_t)((T + 1) * 64 + 32 + row) * 64 + ccg * 8,
                  Ks[par ^ 1] + 2048 + (size_t)w * 512);
        #pragma unroll
        for (int sub = 0; sub < 2; sub++)
          #pragma unroll
          for (int p = 0; p < 2; p++) {
            int id = p * 256 + t, vr = id >> 2, vc = id & 3;
            int vcg = vc ^ (vr & 3) ^ ((vr >> 2) & 3);
            GLD_LDS16(Vp + (size_t)((T + 1) * 2 + sub) * 4096 + vr * 32 + vcg * 8,
                      Vs[par ^ 1] + sub * 4096 + (size_t)(p * 256 + w * 64) * 8);
          }
      }
      #pragma unroll
      for (int sub = 0; sub < 2; sub++) {
        const int kt = T * 2 + sub;
        if (kt * 32 <= rw + 31) {
          const u16* Kc = Ks[par] + sub * 2048;
          const u16* Vc = Vs[par] + sub * 4096;
          f32x4 st[2][2];
          st[0][0] = st[0][1] = st[1][0] = st[1][1] = (f32x4){0.f, 0.f, 0.f, 0.f};
          #pragma unroll
          for (int kb2 = 0; kb2 < 2; kb2++) {
            int krow = kb2 * 16 + n;
            #pragma unroll
            for (int c = 0; c < 2; c++) {
              bf16x8 kf = *(const bf16x8*)(Kc + (size_t)krow * 64 + (((c * 4 + g) ^ (n & 7)) * 8));
              st[0][kb2] = __builtin_amdgcn_mfma_f32_16x16x32_bf16(kf, qf[0][c], st[0][kb2], 0, 0, 0);
              st[1][kb2] = __builtin_amdgcn_mfma_f32_16x16x32_bf16(kf, qf[1][c], st[1][kb2], 0, 0, 0);
            }
          }
          if (kt * 32 + 31 > rw) {
            #pragma unroll
            for (int q2 = 0; q2 < 2; q2++)
              #pragma unroll
              for (int kb2 = 0; kb2 < 2; kb2++)
                #pragma unroll
                for (int r = 0; r < 4; r++)
                  if (kt * 32 + kb2 * 16 + g * 4 + r > rw + q2 * 16 + n) st[q2][kb2][r] = -1e30f;
          }
          #pragma unroll
          for (int q2 = 0; q2 < 2; q2++) {
            int Prow = q2 * 16 + n;
            #pragma unroll
            for (int kb2 = 0; kb2 < 2; kb2++) {
              float p0 = exp2f(st[q2][kb2][0]), p1 = exp2f(st[q2][kb2][1]);
              float p2 = exp2f(st[q2][kb2][2]), p3 = exp2f(st[q2][kb2][3]);
              lsum[q2] += (p0 + p1) + (p2 + p3);
              uint2 dd;
              dd.x = pk2(p0, p1);
              dd.y = pk2(p2, p3);
              *(uint2*)(Pw + (size_t)Prow * 32 + (((kb2 * 4 + g) ^ (n & 6)) * 4)) = dd;
            }
          }
          bf16x8 pf0 = *(const bf16x8*)(Pw + (size_t)n * 32 + (((2 * g) ^ (n & 6)) * 4));
          bf16x8 pf1 = *(const bf16x8*)(Pw + (size_t)(16 + n) * 32 + (((2 * g) ^ (n & 6)) * 4));
          #pragma unroll
          for (int nb = 0; nb < 8; nb++) {
            int dv = nb * 16 + n;
            bf16x8 vf = *(const bf16x8*)(Vc + (size_t)dv * 32 + ((g ^ (n & 3) ^ ((n >> 2) & 3)) * 8));
            o_acc[0][nb] = __builtin_amdgcn_mfma_f32_16x16x32_bf16(pf0, vf, o_acc[0][nb], 0, 0, 0);
            o_acc[1][nb] = __builtin_amdgcn_mfma_f32_16x16x32_bf16(pf1, vf, o_acc[1][nb], 0, 0, 0);
          }
        }
      }
    }
    #pragma unroll
    for (int q2 = 0; q2 < 2; q2++) {
      lsum[q2] += __shfl_xor(lsum[q2], 16);
      lsum[q2] += __shfl_xor(lsum[q2], 32);
    }
    u16* Op = Od + (size_t)inst * SEQ * 128;
    #pragma unroll
    for (int q2 = 0; q2 < 2; q2++)
      #pragma unroll
      for (int nb = 0; nb < 8; nb++)
        #pragma unroll
        for (int r = 0; r < 4; r++) {
          int qrow = rw + q2 * 16 + g * 4 + r;
          Op[(size_t)qrow * 128 + nb * 16 + n] = f2bf(o_acc[q2][nb][r]);
        }
    if (l < 16) {
      Ld[(size_t)inst * SEQ + rw + n]      = lsum[0];
      Ld[(size_t)inst * SEQ + rw + 16 + n] = lsum[1];
    }
  }
}

// ---------------- combine: lambda (in-wave) + merge split-K partials,
// attn1 - lam*attn2, RMSNorm(128), subln, (1-lambda_init) ----------------
__global__ __launch_bounds__(256) void k_combine(const u16* __restrict__ PA,
                                                 const u16* __restrict__ PB,
                                                 const float* __restrict__ LA,
                                                 const float* __restrict__ LB,
                                                 const float* __restrict__ lq1,
                                                 const float* __restrict__ lk1,
                                                 const float* __restrict__ lq2,
                                                 const float* __restrict__ lk2,
                                                 const float* __restrict__ subw,
                                                 u16* __restrict__ At) {
  const int t = threadIdx.x, w = t >> 6, l = t & 63;
  float s1 = lq1[l] * lk1[l];
  float s2 = lq2[l] * lk2[l];
  #pragma unroll
  for (int d = 1; d < 64; d <<= 1) { s1 += __shfl_xor(s1, d); s2 += __shfl_xor(s2, d); }
  const float lam = expf(s1) - expf(s2) + LAMBDA_INIT;
  const int W = blockIdx.x * 4 + w;          // (b*SEQ+s)*16 + h
  const int hh = W & 15, row = W >> 4;
  const int b = row >> 11, s = row & (SEQ - 1);
  const int e1 = b * 32 + hh * 2;
  const size_t base1 = ((size_t)e1 * SEQ + s) * 128 + 2 * l;
  const size_t base2 = base1 + (size_t)SEQ * 128;
  uint32_t u1a = *(const uint32_t*)(PA + base1);
  uint32_t u1b = *(const uint32_t*)(PB + base1);
  uint32_t u2a = *(const uint32_t*)(PA + base2);
  uint32_t u2b = *(const uint32_t*)(PB + base2);
  float inv1 = 1.0f / (LA[(size_t)e1 * SEQ + s] + LB[(size_t)e1 * SEQ + s]);
  float inv2 = 1.0f / (LA[(size_t)(e1 + 1) * SEQ + s] + LB[(size_t)(e1 + 1) * SEQ + s]);
  float o10 = (bf2f(u1a & 0xffffu) + bf2f(u1b & 0xffffu)) * inv1;
  float o11 = (bf2f(u1a >> 16) + bf2f(u1b >> 16)) * inv1;
  float o20 = (bf2f(u2a & 0xffffu) + bf2f(u2b & 0xffffu)) * inv2;
  float o21 = (bf2f(u2a >> 16) + bf2f(u2b >> 16)) * inv2;
  float a0 = o10 - lam * o20;
  float a1 = o11 - lam * o21;
  float ss = a0 * a0 + a1 * a1;
  #pragma unroll
  for (int d = 1; d < 64; d <<= 1) ss += __shfl_xor(ss, d);
  float rms = rsqrtf(ss * (1.0f / 128.0f) + EPSF);
  float k = rms * (1.0f - LAMBDA_INIT);
  *(uint32_t*)(At + (size_t)row * MDIM + hh * 128 + 2 * l) =
      pk2(a0 * subw[2 * l] * k, a1 * subw[2 * l + 1] * k);
}

// ---------------- host ----------------
extern "C" void kernel_launch(void* const* d_in, const int* in_sizes, int n_in,
                              void* d_out, int out_size, void* d_ws, size_t ws_size,
                              hipStream_t stream) {
  const float* x    = (const float*)d_in[0];
  const float* wq   = (const float*)d_in[1];
  const float* wk   = (const float*)d_in[2];
  const float* wv   = (const float*)d_in[3];
  const float* wo   = (const float*)d_in[4];
  const float* lq1  = (const float*)d_in[5];
  const float* lk1  = (const float*)d_in[6];
  const float* lq2  = (const float*)d_in[7];
  const float* lk2  = (const float*)d_in[8];
  const float* subw = (const float*)d_in[9];
  const float* rc   = (const float*)d_in[10];
  const float* rsn  = (const float*)d_in[11];

  char* ws = (char*)d_ws;
  u16*   Xbf  = (u16*)(ws + 0);            // 16.78 MB (dead after GEMM1 -> LA/LB)
  u16*   Wqkv = (u16*)(ws + 16777216);     // 25.17 MB (dead after GEMM1 -> At)
  u16*   Wob  = (u16*)(ws + 41943040);     //  8.39 MB
  float* CSb  = (float*)(ws + 50331648);   //  0.52 MB cos/sin float2 table
  u16*   Qb   = (u16*)(ws + 50855936);     // 16.78 MB
  u16*   Kb   = (u16*)(ws + 67633152);     // 16.78 MB
  u16*   Vt   = (u16*)(ws + 101187584);    // 16.78 MB tiled [bh][kt32][dv][key]
  u16*   ObA  = (u16*)(ws + 117964800);    // 33.55 MB split-K partial A
  u16*   ObB  = (u16*)(ws + 151519232);    // 33.55 MB split-K partial B
  float* LA   = (float*)(ws + 0);          // aliases dead Xbf
  float* LB   = (float*)(ws + 524288);
  u16*   At   = Wqkv;                      // aliases dead Wqkv
  if (ws_size < 185073664) return;

  k_castall<<<24640, 256, 0, stream>>>((const float4*)x, (const float4*)wq,
                                       (const float4*)wk, (const float4*)wv,
                                       (const float4*)wo, (const float4*)rc,
                                       (const float4*)rsn,
                                       Xbf, Wqkv, Wob, (float4*)CSb);
  k_gemm_qkv<<<dim3(384), 512, 0, stream>>>(Xbf, Wqkv, (const float2*)CSb,
                                            Qb, Kb, Vt);
  k_flash<<<1024, 256, 0, stream>>>(Qb, Kb, Vt, ObA, ObB, LA, LB);
  k_combine<<<16384, 256, 0, stream>>>(ObA, ObB, LA, LB, lq1, lk1, lq2, lk2, subw, At);
  k_gemm_bt<0><<<dim3(16, 32), 256, 0, stream>>>(At, Wob, d_out, NROWS, MDIM, MDIM);
}

// Round 9
// 410.792 us; speedup vs baseline: 1.0152x; 1.0152x over previous
//
#include <hip/hip_runtime.h>
#include <hip/hip_bf16.h>
#include <stdint.h>

// Problem constants
#define SEQ   2048
#define NHEAD 16
#define DHEAD 64
#define NROWS 4096      // BSZ*SEQ
#define MDIM  2048      // model dim
#define QKVN  6144
#define EPSF  1e-5f
#define LAMBDA_INIT 0.7999593627581f
#define QSCALE 0.18033688011112042f   // dh^-0.5 * log2(e): flash softmax runs in exp2 domain

typedef unsigned short u16;
typedef __attribute__((ext_vector_type(8))) short bf16x8;   // 8 bf16 = 4 VGPRs
typedef __attribute__((ext_vector_type(4))) float f32x4;
typedef __attribute__((ext_vector_type(4))) unsigned short u16x4;

// async global->LDS, 16B/lane: data lands at LDS base + lane*16 (wave-uniform base).
#define GLD_LDS16(g, l) \
  __builtin_amdgcn_global_load_lds((const __attribute__((address_space(1))) void*)(g), \
                                   (__attribute__((address_space(3))) void*)(l), 16, 0, 0)

__device__ __forceinline__ u16 f2bf(float f) {
  union { float f; uint32_t u; } v; v.f = f;
  return (u16)((v.u + 0x7fffu + ((v.u >> 16) & 1u)) >> 16);   // RNE
}
__device__ __forceinline__ float bf2f(uint32_t s) {
  union { uint32_t u; float f; } v; v.u = s << 16; return v.f;
}
// packed fp32x2 -> bf16x2 (gfx950 v_cvt_pk_bf16_f32 via HIP API), RNE
__device__ __forceinline__ uint32_t pk2(float a, float b) {
  __hip_bfloat162 h = __float22bfloat162_rn(make_float2(a, b));
  union { __hip_bfloat162 h; uint32_t u; } v; v.h = h; return v.u;
}

// ---------------- unified cast: x, 4 weights, cos/sin float2 table ----------
__global__ __launch_bounds__(256) void k_castall(const float4* __restrict__ x,
                                                 const float4* __restrict__ wq,
                                                 const float4* __restrict__ wk,
                                                 const float4* __restrict__ wv,
                                                 const float4* __restrict__ wo,
                                                 const float4* __restrict__ rc,
                                                 const float4* __restrict__ rsn,
                                                 u16* __restrict__ Xbf,
                                                 u16* __restrict__ Wqkv,
                                                 u16* __restrict__ Wob,
                                                 float4* __restrict__ CS) {
  int bid = blockIdx.x, t = threadIdx.x;
  if (bid < 8192) {                       // x: 2.097M float4
    int i = bid * 256 + t;
    float4 f = x[i];
    u16x4 o; o.x = f2bf(f.x); o.y = f2bf(f.y); o.z = f2bf(f.z); o.w = f2bf(f.w);
    *(u16x4*)(Xbf + (size_t)i * 4) = o;
  } else if (bid < 24576) {               // 4 weights x 1.048M float4
    int widx = (bid - 8192) >> 12;
    int i = ((bid - 8192) & 4095) * 256 + t;
    const float4* s = widx == 0 ? wq : widx == 1 ? wk : widx == 2 ? wv : wo;
    u16* d = widx < 3 ? (Wqkv + (size_t)widx * 4194304) : Wob;
    float4 f = s[i];
    u16x4 o; o.x = f2bf(f.x); o.y = f2bf(f.y); o.z = f2bf(f.z); o.w = f2bf(f.w);
    *(u16x4*)(d + (size_t)i * 4) = o;
  } else {                                // CS[s*32+i] = (cos, sin) float2; 16384 f4
    int j = (bid - 24576) * 256 + t;
    float4 c = rc[j], s = rsn[j];
    CS[(size_t)j * 2]     = make_float4(c.x, s.x, c.y, s.y);
    CS[(size_t)j * 2 + 1] = make_float4(c.z, s.z, c.w, s.w);
  }
}

// ---------------- GEMM1, 256x256 8-phase counted-vmcnt (R8 best: ~130us) ----
#define PH_BAR asm volatile("s_barrier" ::: "memory")
#define VMW8   asm volatile("s_waitcnt vmcnt(8)" ::: "memory")
#define VMW6   asm volatile("s_waitcnt vmcnt(6)" ::: "memory")
#define VMW0   asm volatile("s_waitcnt vmcnt(0)" ::: "memory")

// stage one half-tile (128 rows x 64 cols bf16 = 2 x 8KB block-wide loads)
#define STAGEH(Gb, dst, r0, kt) do { \
  GLD_LDS16((Gb) + (size_t)(r0) * MDIM + (kt) * 64,        (dst) + (r0) * 64 + wofs); \
  GLD_LDS16((Gb) + (size_t)((r0) + 64) * MDIM + (kt) * 64, (dst) + ((r0) + 64) * 64 + wofs); \
} while (0)

#define RDA(base, mi0) do { \
  _Pragma("unroll") for (int mi = 0; mi < 4; mi++) { \
    const int ar = wr * 128 + ((mi0) + mi) * 16 + n; \
    _Pragma("unroll") for (int kk = 0; kk < 2; kk++) \
      af[mi][kk] = *(const bf16x8*)((base) + ((size_t)ar * 8 + (((kk * 4 + g) ^ ar) & 7)) * 8); \
  } } while (0)

#define RDB(dst, base, ni0) do { \
  _Pragma("unroll") for (int nj = 0; nj < 2; nj++) { \
    const int br = wc * 64 + ((ni0) + nj) * 16 + n; \
    _Pragma("unroll") for (int kk = 0; kk < 2; kk++) \
      dst[nj][kk] = *(const bf16x8*)((base) + ((size_t)br * 8 + (((kk * 4 + g) ^ br) & 7)) * 8); \
  } } while (0)

#define MMQ(mi0, ni0, bf) do { \
  __builtin_amdgcn_s_setprio(1); \
  _Pragma("unroll") for (int mi = 0; mi < 4; mi++) \
    _Pragma("unroll") for (int nj = 0; nj < 2; nj++) \
      _Pragma("unroll") for (int kk = 0; kk < 2; kk++) \
        acc[(mi0) + mi][(ni0) + nj] = __builtin_amdgcn_mfma_f32_16x16x32_bf16( \
            af[mi][kk], bf[nj][kk], acc[(mi0) + mi][(ni0) + nj], 0, 0, 0); \
  __builtin_amdgcn_s_setprio(0); \
} while (0)

__global__ __launch_bounds__(512, 2) void k_gemm_qkv(const u16* __restrict__ A,
                                                     const u16* __restrict__ B,
                                                     const float2* __restrict__ CS2,
                                                     u16* __restrict__ Qb,
                                                     u16* __restrict__ Kb,
                                                     u16* __restrict__ Vt) {
  __shared__ __align__(16) u16 As[2][16384];   // [slot][256 rows][64 cols]
  __shared__ __align__(16) u16 Bs[2][16384];
  const int t = threadIdx.x, w = t >> 6, l = t & 63, n = l & 15, g = (l >> 4) & 3;
  const int wr = w >> 2, wc = w & 3;
  // bijective XCD swizzle: 384 blocks, 48 per XCD, contiguous tile chunks
  const int bid = blockIdx.x;
  const int swz = (bid & 7) * 48 + (bid >> 3);
  const int by = swz / 24, bx = swz - by * 24;
  const int m0 = by * 256, n0 = bx * 256;

  // staging: thread t covers (row = t>>3, chunk cc = t&7); source chunk is
  // pre-swizzled (cc ^ row) so LDS stays linear for global_load_lds.
  const int srow = t >> 3, scg = ((t & 7) ^ srow) & 7;
  const u16* Ag = A + (size_t)(m0 + srow) * MDIM + scg * 8;
  const u16* Bg = B + (size_t)(n0 + srow) * MDIM + scg * 8;
  const int wofs = w * 512;                    // per-wave LDS dest (u16)

  f32x4 acc[8][4];
  #pragma unroll
  for (int i = 0; i < 8; i++)
    #pragma unroll
    for (int j = 0; j < 4; j++) acc[i][j] = (f32x4){0.f, 0.f, 0.f, 0.f};
  bf16x8 af[4][2], b0[2][2], b1[2][2];

  u16* const A0 = As[0]; u16* const A1 = As[1];
  u16* const B0 = Bs[0]; u16* const B1 = Bs[1];

  // prologue: tiles 0 (slot0) then 1 (slot1); tile0 = oldest 8 loads
  STAGEH(Ag, A0, 0, 0);  STAGEH(Ag, A0, 128, 0);
  STAGEH(Bg, B0, 0, 0);  STAGEH(Bg, B0, 128, 0);
  STAGEH(Ag, A1, 0, 1);  STAGEH(Ag, A1, 128, 1);
  STAGEH(Bg, B1, 0, 1);  STAGEH(Bg, B1, 128, 1);
  VMW8; PH_BAR;

  #pragma unroll 1
  for (int i = 0; i < 16; ++i) {
    const int t1 = 2 * i + 1, t2 = 2 * i + 2, t3 = 2 * i + 3;
    // ---- P1: reads slot0 A[qm0]+B[qn0]; stage A1-hi(t1)
    RDA(A0, 0); RDB(b0, B0, 0);
    if (i >= 1) STAGEH(Ag, A1, 128, t1);
    PH_BAR; MMQ(0, 0, b0); PH_BAR;
    // ---- P2: reads B[qn1]
    RDB(b1, B0, 2);
    PH_BAR; MMQ(0, 2, b1); PH_BAR;
    // ---- P3: reads A[qm1]; stage B0-lo(t2) + B0-hi(t2) (B0 dead after P2)
    RDA(A0, 4);
    if (i < 15) { STAGEH(Bg, B0, 0, t2); STAGEH(Bg, B0, 128, t2); }
    PH_BAR; MMQ(4, 2, b1); PH_BAR;
    // ---- P4: regs only; stage A0-lo(t2); gate vmcnt(6)
    if (i < 15) STAGEH(Ag, A0, 0, t2);
    PH_BAR; MMQ(4, 0, b0);
    if (i < 15) { VMW6; } else { VMW0; }
    PH_BAR;
    // ---- P5: reads slot1 A[qm0]+B[qn0]; stage A0-hi(t2)
    RDA(A1, 0); RDB(b0, B1, 0);
    if (i < 15) STAGEH(Ag, A0, 128, t2);
    PH_BAR; MMQ(0, 0, b0); PH_BAR;
    // ---- P6: reads B[qn1]
    RDB(b1, B1, 2);
    PH_BAR; MMQ(0, 2, b1); PH_BAR;
    // ---- P7: reads A[qm1]; stage B1-lo(t3) + B1-hi(t3) (B1 dead after P6)
    RDA(A1, 4);
    if (i < 15) { STAGEH(Bg, B1, 0, t3); STAGEH(Bg, B1, 128, t3); }
    PH_BAR; MMQ(4, 2, b1); PH_BAR;
    // ---- P8: stage A1-lo(t3); gate vmcnt(6)
    if (i < 15) STAGEH(Ag, A1, 0, t3);
    PH_BAR; MMQ(4, 0, b0);
    if (i < 15) VMW6;
    PH_BAR;
  }

  // ---- epilogue: fused RoPE (Q/K) or direct-transposed V (Q=bx0..7,
  // K=8..15, V=16..23)
  if (bx < 16) {                                  // Q (bx<8) or K block
    const float scale = bx < 8 ? QSCALE : 1.0f;
    u16* outb = bx < 8 ? Qb : Kb;
    const float sgn = (n & 1) ? 1.0f : -1.0f;
    #pragma unroll
    for (int mi = 0; mi < 8; mi++)
      #pragma unroll
      for (int r = 0; r < 4; r++) {
        const int row = m0 + wr * 128 + mi * 16 + g * 4 + r;
        const int s = row & (SEQ - 1);
        #pragma unroll
        for (int ni = 0; ni < 4; ni++) {
          const int cl = wc * 64 + ni * 16 + n;
          float val = acc[mi][ni][r];
          float par = __shfl_xor(val, 1);
          float2 cs = CS2[(size_t)s * 32 + ((cl >> 1) & 31)];
          float o = (val * cs.x + sgn * par * cs.y) * scale;
          const int col = n0 + cl;
          const int inst = (row >> 11) * 32 + ((col >> 6) & 31);
          outb[((size_t)inst * SEQ + s) * 64 + (col & 63)] = f2bf(o);
        }
      }
  } else {                                        // V block -> tiled Vt direct
    // Vt[((bh*64 + s>>5)*128 + dv)*32 + (s&31)] = V[b*SEQ+s][h*128+dv]
    const int vb = (bx - 16) * 256;
    #pragma unroll
    for (int mi = 0; mi < 8; mi++) {
      const int row0 = m0 + wr * 128 + mi * 16 + g * 4;
      const int s0 = row0 & (SEQ - 1);
      const int bb = row0 >> 11;
      #pragma unroll
      for (int ni = 0; ni < 4; ni++) {
        const int vcol = vb + wc * 64 + ni * 16 + n;
        const int hh = vcol >> 7, dv = vcol & 127;
        const int bh2 = bb * 16 + hh;
        u16x4 pk;
        pk.x = f2bf(acc[mi][ni][0]);
        pk.y = f2bf(acc[mi][ni][1]);
        pk.z = f2bf(acc[mi][ni][2]);
        pk.w = f2bf(acc[mi][ni][3]);
        *(u16x4*)(Vt + ((size_t)(bh2 * 64 + (s0 >> 5)) * 128 + dv) * 32 + (s0 & 31)) = pk;
      }
    }
  }
}

// ---------------- GEMM2 (R9): 8-phase counted-vmcnt port, BM=128 x BN=256 ---
// d_out = At @ Wob^T, fp32 out. Grid 32x8 = 256 blocks = EXACTLY 1 round.
// 8 waves (2M x 4N), wave tile 64x64, acc[4][4]. LDS 96 KB (A 2x16K, B 2x32K).
// Liveness: A (1 unit) fully read at P1/P5; B units each read at P1+P2 /
// P5+P6 (both wc-halves touch both units) -> B dead after P2/P6.
// Staging: P3:{B0(t2) x2u} P4:{A0(t2)} P6:{A1(t3)} P7:{B1(t3) x2u}.
// Gates vmcnt(6) at P4/P8: outstanding = this half-iter's 6 loads; the tile
// consumed next was staged >=5 phases earlier (retired). K accumulation
// order identical to the old 128^2 kernel (64-tiles ascending, kk pairs).
#define RDA128(base) do { \
  _Pragma("unroll") for (int mi = 0; mi < 4; mi++) { \
    const int ar = wr * 64 + mi * 16 + n; \
    _Pragma("unroll") for (int kk = 0; kk < 2; kk++) \
      af[mi][kk] = *(const bf16x8*)((base) + ((size_t)ar * 8 + (((kk * 4 + g) ^ ar) & 7)) * 8); \
  } } while (0)

#define MMQ8(mi0, ni0, bf) do { \
  __builtin_amdgcn_s_setprio(1); \
  _Pragma("unroll") for (int mi = 0; mi < 2; mi++) \
    _Pragma("unroll") for (int nj = 0; nj < 2; nj++) \
      _Pragma("unroll") for (int kk = 0; kk < 2; kk++) \
        acc[(mi0) + mi][(ni0) + nj] = __builtin_amdgcn_mfma_f32_16x16x32_bf16( \
            af[(mi0) + mi][kk], bf[nj][kk], acc[(mi0) + mi][(ni0) + nj], 0, 0, 0); \
  __builtin_amdgcn_s_setprio(0); \
} while (0)

__global__ __launch_bounds__(512, 2) void k_gemm_o(const u16* __restrict__ A,
                                                   const u16* __restrict__ B,
                                                   float* __restrict__ C) {
  __shared__ __align__(16) u16 As[2][8192];    // [slot][128 rows][64 cols]
  __shared__ __align__(16) u16 Bs[2][16384];   // [slot][256 rows][64 cols]
  const int t = threadIdx.x, w = t >> 6, l = t & 63, n = l & 15, g = (l >> 4) & 3;
  const int wr = w >> 2, wc = w & 3;
  // XCD swizzle: 256 blocks, 32/XCD (4 by-rows x 8 bx)
  const int bid = blockIdx.x;
  const int swz = (bid & 7) * 32 + (bid >> 3);
  const int by = swz >> 3, bx = swz & 7;
  const int m0 = by * 128, n0 = bx * 256;

  const int srow = t >> 3, scg = ((t & 7) ^ srow) & 7;
  const u16* Ag = A + (size_t)(m0 + srow) * MDIM + scg * 8;
  const u16* Bg = B + (size_t)(n0 + srow) * MDIM + scg * 8;
  const int wofs = w * 512;

  f32x4 acc[4][4];
  #pragma unroll
  for (int i = 0; i < 4; i++)
    #pragma unroll
    for (int j = 0; j < 4; j++) acc[i][j] = (f32x4){0.f, 0.f, 0.f, 0.f};
  bf16x8 af[4][2], b0[2][2], b1[2][2];

  u16* const A0 = As[0]; u16* const A1 = As[1];
  u16* const B0 = Bs[0]; u16* const B1 = Bs[1];

  // prologue: tile0 (6 loads, oldest), tile1 (6 loads)
  STAGEH(Ag, A0, 0, 0);
  STAGEH(Bg, B0, 0, 0); STAGEH(Bg, B0, 128, 0);
  STAGEH(Ag, A1, 0, 1);
  STAGEH(Bg, B1, 0, 1); STAGEH(Bg, B1, 128, 1);
  VMW6; PH_BAR;

  #pragma unroll 1
  for (int i = 0; i < 16; ++i) {
    const int t2 = 2 * i + 2, t3 = 2 * i + 3;
    // ---- P1: reads slot0 A(all) + B frags 0,1
    RDA128(A0); RDB(b0, B0, 0);
    PH_BAR; MMQ8(0, 0, b0); PH_BAR;
    // ---- P2: reads B frags 2,3
    RDB(b1, B0, 2);
    PH_BAR; MMQ8(0, 2, b1); PH_BAR;
    // ---- P3: stage B0(t2) (B0 dead after P2)
    if (i < 15) { STAGEH(Bg, B0, 0, t2); STAGEH(Bg, B0, 128, t2); }
    PH_BAR; MMQ8(2, 2, b1); PH_BAR;
    // ---- P4: stage A0(t2) (A0 dead after P1); gate vmcnt(6)
    if (i < 15) STAGEH(Ag, A0, 0, t2);
    PH_BAR; MMQ8(2, 0, b0);
    if (i < 15) { VMW6; } else { VMW0; }
    PH_BAR;
    // ---- P5: reads slot1 A(all) + B frags 0,1
    RDA128(A1); RDB(b0, B1, 0);
    PH_BAR; MMQ8(0, 0, b0); PH_BAR;
    // ---- P6: reads B frags 2,3; stage A1(t3) (A1 dead after P5)
    RDB(b1, B1, 2);
    if (i < 15) STAGEH(Ag, A1, 0, t3);
    PH_BAR; MMQ8(0, 2, b1); PH_BAR;
    // ---- P7: stage B1(t3) (B1 dead after P6)
    if (i < 15) { STAGEH(Bg, B1, 0, t3); STAGEH(Bg, B1, 128, t3); }
    PH_BAR; MMQ8(2, 2, b1); PH_BAR;
    // ---- P8: gate vmcnt(6)
    PH_BAR; MMQ8(2, 0, b0);
    if (i < 15) VMW6;
    PH_BAR;
  }

  // ---- epilogue: plain fp32 store (coalesced 16-lane runs)
  #pragma unroll
  for (int mi = 0; mi < 4; mi++)
    #pragma unroll
    for (int ni = 0; ni < 4; ni++)
      #pragma unroll
      for (int r = 0; r < 4; r++) {
        const int row = m0 + wr * 64 + mi * 16 + g * 4 + r;
        const int col = n0 + wc * 64 + ni * 16 + n;
        C[(size_t)row * MDIM + col] = acc[mi][ni][r];
      }
}

// ---------------- flash attention v11: KVBLK=64 staging/barrier granularity.
// (R6-measured WIN; unchanged)
__global__ __launch_bounds__(256, 2) void k_flash(const u16* __restrict__ Q,
                                                  const u16* __restrict__ K,
                                                  const u16* __restrict__ V,
                                                  u16* __restrict__ PA, u16* __restrict__ PB,
                                                  float* __restrict__ LA, float* __restrict__ LB) {
  __shared__ __align__(16) u16 Ks[2][64 * 64];    // 8KB/buf: two 32x64 sub-tiles
  __shared__ __align__(16) u16 Vs[2][128 * 64];   // 16KB/buf: two [128dv][32key] sub-tiles
  __shared__ __align__(16) u16 Ps[4][32 * 32];
  const int t = threadIdx.x, w = t >> 6, l = t & 63, n = l & 15, g = l >> 4;
  const int gb = blockIdx.x;
  const int xcd = gb & 7, qq = gb >> 3, j = qq & 15, ihi = qq >> 4;
  const int inst = ihi * 8 + xcd;
  const int b = inst >> 5, rh = inst & 31, h = rh >> 1, bh = b * 16 + h;
  const u16* Qp = Q + (size_t)inst * SEQ * 64;
  const u16* Kp = K + (size_t)inst * SEQ * 64;
  const u16* Vp = V + (size_t)bh * 262144;
  u16* Pw = Ps[w];

  #pragma unroll
  for (int ch = 0; ch < 2; ch++) {
    const int tile = ch ? j : (15 - j);
    const int k0 = ch ? (2 * j + 2) : 0;          // 32-key units (always even)
    const int k1 = ch ? (4 * j + 4) : (32 - 2 * j);
    const int T0 = k0 >> 1, T1 = k1 >> 1;         // 64-key tiles
    const int rw = tile * 128 + w * 32;
    u16* Od = ch ? PB : PA;
    float* Ld = ch ? LB : LA;

    bf16x8 qf[2][2];
    #pragma unroll
    for (int q2 = 0; q2 < 2; q2++)
      #pragma unroll
      for (int c = 0; c < 2; c++)
        qf[q2][c] = *(const bf16x8*)(Qp + (size_t)(rw + q2 * 16 + n) * 64 + c * 32 + g * 8);

    f32x4 o_acc[2][8];
    #pragma unroll
    for (int q2 = 0; q2 < 2; q2++)
      #pragma unroll
      for (int nb = 0; nb < 8; nb++) o_acc[q2][nb] = (f32x4){0.f, 0.f, 0.f, 0.f};
    float lsum[2] = {0.f, 0.f};

    __syncthreads();
    {   // stage 64-key tile T0 -> buffer 0
      int row = t >> 3, cc = t & 7, ccg = cc ^ (row & 7);
      GLD_LDS16(Kp + (size_t)(T0 * 64 + row) * 64 + ccg * 8,      Ks[0] + (size_t)w * 512);
      GLD_LDS16(Kp + (size_t)(T0 * 64 + 32 + row) * 64 + ccg * 8, Ks[0] + 2048 + (size_t)w * 512);
      #pragma unroll
      for (int sub = 0; sub < 2; sub++)
        #pragma unroll
        for (int p = 0; p < 2; p++) {
          int id = p * 256 + t, vr = id >> 2, vc = id & 3;
          int vcg = vc ^ (vr & 3) ^ ((vr >> 2) & 3);
          GLD_LDS16(Vp + (size_t)(T0 * 2 + sub) * 4096 + vr * 32 + vcg * 8,
                    Vs[0] + sub * 4096 + (size_t)(p * 256 + w * 64) * 8);
        }
    }

    for (int T = T0; T < T1; ++T) {
      const int par = (T - T0) & 1;
      __syncthreads();
      if (T + 1 < T1) {
        int row = t >> 3, cc = t & 7, ccg = cc ^ (row & 7);
        GLD_LDS16(Kp + (size_t)((T + 1) * 64 + row) * 64 + ccg * 8,
                  Ks[par ^ 1] + (size_t)w * 512);
        GLD_LDS16(Kp + (size_t)((T + 1) * 64 + 32 + row) * 64 + ccg * 8,
                  Ks[par ^ 1] + 2048 + (size_t)w * 512);
        #pragma unroll
        for (int sub = 0; sub < 2; sub++)
          #pragma unroll
          for (int p = 0; p < 2; p++) {
            int id = p * 256 + t, vr = id >> 2, vc = id & 3;
            int vcg = vc ^ (vr & 3) ^ ((vr >> 2) & 3);
            GLD_LDS16(Vp + (size_t)((T + 1) * 2 + sub) * 4096 + vr * 32 + vcg * 8,
                      Vs[par ^ 1] + sub * 4096 + (size_t)(p * 256 + w * 64) * 8);
          }
      }
      #pragma unroll
      for (int sub = 0; sub < 2; sub++) {
        const int kt = T * 2 + sub;
        if (kt * 32 <= rw + 31) {
          const u16* Kc = Ks[par] + sub * 2048;
          const u16* Vc = Vs[par] + sub * 4096;
          f32x4 st[2][2];
          st[0][0] = st[0][1] = st[1][0] = st[1][1] = (f32x4){0.f, 0.f, 0.f, 0.f};
          #pragma unroll
          for (int kb2 = 0; kb2 < 2; kb2++) {
            int krow = kb2 * 16 + n;
            #pragma unroll
            for (int c = 0; c < 2; c++) {
              bf16x8 kf = *(const bf16x8*)(Kc + (size_t)krow * 64 + (((c * 4 + g) ^ (n & 7)) * 8));
              st[0][kb2] = __builtin_amdgcn_mfma_f32_16x16x32_bf16(kf, qf[0][c], st[0][kb2], 0, 0, 0);
              st[1][kb2] = __builtin_amdgcn_mfma_f32_16x16x32_bf16(kf, qf[1][c], st[1][kb2], 0, 0, 0);
            }
          }
          if (kt * 32 + 31 > rw) {
            #pragma unroll
            for (int q2 = 0; q2 < 2; q2++)
              #pragma unroll
              for (int kb2 = 0; kb2 < 2; kb2++)
                #pragma unroll
                for (int r = 0; r < 4; r++)
                  if (kt * 32 + kb2 * 16 + g * 4 + r > rw + q2 * 16 + n) st[q2][kb2][r] = -1e30f;
          }
          #pragma unroll
          for (int q2 = 0; q2 < 2; q2++) {
            int Prow = q2 * 16 + n;
            #pragma unroll
            for (int kb2 = 0; kb2 < 2; kb2++) {
              float p0 = exp2f(st[q2][kb2][0]), p1 = exp2f(st[q2][kb2][1]);
              float p2 = exp2f(st[q2][kb2][2]), p3 = exp2f(st[q2][kb2][3]);
              lsum[q2] += (p0 + p1) + (p2 + p3);
              uint2 dd;
              dd.x = pk2(p0, p1);
              dd.y = pk2(p2, p3);
              *(uint2*)(Pw + (size_t)Prow * 32 + (((kb2 * 4 + g) ^ (n & 6)) * 4)) = dd;
            }
          }
          bf16x8 pf0 = *(const bf16x8*)(Pw + (size_t)n * 32 + (((2 * g) ^ (n & 6)) * 4));
          bf16x8 pf1 = *(const bf16x8*)(Pw + (size_t)(16 + n) * 32 + (((2 * g) ^ (n & 6)) * 4));
          #pragma unroll
          for (int nb = 0; nb < 8; nb++) {
            int dv = nb * 16 + n;
            bf16x8 vf = *(const bf16x8*)(Vc + (size_t)dv * 32 + ((g ^ (n & 3) ^ ((n >> 2) & 3)) * 8));
            o_acc[0][nb] = __builtin_amdgcn_mfma_f32_16x16x32_bf16(pf0, vf, o_acc[0][nb], 0, 0, 0);
            o_acc[1][nb] = __builtin_amdgcn_mfma_f32_16x16x32_bf16(pf1, vf, o_acc[1][nb], 0, 0, 0);
          }
        }
      }
    }
    #pragma unroll
    for (int q2 = 0; q2 < 2; q2++) {
      lsum[q2] += __shfl_xor(lsum[q2], 16);
      lsum[q2] += __shfl_xor(lsum[q2], 32);
    }
    u16* Op = Od + (size_t)inst * SEQ * 128;
    #pragma unroll
    for (int q2 = 0; q2 < 2; q2++)
      #pragma unroll
      for (int nb = 0; nb < 8; nb++)
        #pragma unroll
        for (int r = 0; r < 4; r++) {
          int qrow = rw + q2 * 16 + g * 4 + r;
          Op[(size_t)qrow * 128 + nb * 16 + n] = f2bf(o_acc[q2][nb][r]);
        }
    if (l < 16) {
      Ld[(size_t)inst * SEQ + rw + n]      = lsum[0];
      Ld[(size_t)inst * SEQ + rw + 16 + n] = lsum[1];
    }
  }
}

// ---------------- combine: lambda (in-wave) + merge split-K partials,
// attn1 - lam*attn2, RMSNorm(128), subln, (1-lambda_init) ----------------
__global__ __launch_bounds__(256) void k_combine(const u16* __restrict__ PA,
                                                 const u16* __restrict__ PB,
                                                 const float* __restrict__ LA,
                                                 const float* __restrict__ LB,
                                                 const float* __restrict__ lq1,
                                                 const float* __restrict__ lk1,
                                                 const float* __restrict__ lq2,
                                                 const float* __restrict__ lk2,
                                                 const float* __restrict__ subw,
                                                 u16* __restrict__ At) {
  const int t = threadIdx.x, w = t >> 6, l = t & 63;
  float s1 = lq1[l] * lk1[l];
  float s2 = lq2[l] * lk2[l];
  #pragma unroll
  for (int d = 1; d < 64; d <<= 1) { s1 += __shfl_xor(s1, d); s2 += __shfl_xor(s2, d); }
  const float lam = expf(s1) - expf(s2) + LAMBDA_INIT;
  const int W = blockIdx.x * 4 + w;          // (b*SEQ+s)*16 + h
  const int hh = W & 15, row = W >> 4;
  const int b = row >> 11, s = row & (SEQ - 1);
  const int e1 = b * 32 + hh * 2;
  const size_t base1 = ((size_t)e1 * SEQ + s) * 128 + 2 * l;
  const size_t base2 = base1 + (size_t)SEQ * 128;
  uint32_t u1a = *(const uint32_t*)(PA + base1);
  uint32_t u1b = *(const uint32_t*)(PB + base1);
  uint32_t u2a = *(const uint32_t*)(PA + base2);
  uint32_t u2b = *(const uint32_t*)(PB + base2);
  float inv1 = 1.0f / (LA[(size_t)e1 * SEQ + s] + LB[(size_t)e1 * SEQ + s]);
  float inv2 = 1.0f / (LA[(size_t)(e1 + 1) * SEQ + s] + LB[(size_t)(e1 + 1) * SEQ + s]);
  float o10 = (bf2f(u1a & 0xffffu) + bf2f(u1b & 0xffffu)) * inv1;
  float o11 = (bf2f(u1a >> 16) + bf2f(u1b >> 16)) * inv1;
  float o20 = (bf2f(u2a & 0xffffu) + bf2f(u2b & 0xffffu)) * inv2;
  float o21 = (bf2f(u2a >> 16) + bf2f(u2b >> 16)) * inv2;
  float a0 = o10 - lam * o20;
  float a1 = o11 - lam * o21;
  float ss = a0 * a0 + a1 * a1;
  #pragma unroll
  for (int d = 1; d < 64; d <<= 1) ss += __shfl_xor(ss, d);
  float rms = rsqrtf(ss * (1.0f / 128.0f) + EPSF);
  float k = rms * (1.0f - LAMBDA_INIT);
  *(uint32_t*)(At + (size_t)row * MDIM + hh * 128 + 2 * l) =
      pk2(a0 * subw[2 * l] * k, a1 * subw[2 * l + 1] * k);
}

// ---------------- host ----------------
extern "C" void kernel_launch(void* const* d_in, const int* in_sizes, int n_in,
                              void* d_out, int out_size, void* d_ws, size_t ws_size,
                              hipStream_t stream) {
  const float* x    = (const float*)d_in[0];
  const float* wq   = (const float*)d_in[1];
  const float* wk   = (const float*)d_in[2];
  const float* wv   = (const float*)d_in[3];
  const float* wo   = (const float*)d_in[4];
  const float* lq1  = (const float*)d_in[5];
  const float* lk1  = (const float*)d_in[6];
  const float* lq2  = (const float*)d_in[7];
  const float* lk2  = (const float*)d_in[8];
  const float* subw = (const float*)d_in[9];
  const float* rc   = (const float*)d_in[10];
  const float* rsn  = (const float*)d_in[11];

  char* ws = (char*)d_ws;
  u16*   Xbf  = (u16*)(ws + 0);            // 16.78 MB (dead after GEMM1 -> LA/LB)
  u16*   Wqkv = (u16*)(ws + 16777216);     // 25.17 MB (dead after GEMM1 -> At)
  u16*   Wob  = (u16*)(ws + 41943040);     //  8.39 MB
  float* CSb  = (float*)(ws + 50331648);   //  0.52 MB cos/sin float2 table
  u16*   Qb   = (u16*)(ws + 50855936);     // 16.78 MB
  u16*   Kb   = (u16*)(ws + 67633152);     // 16.78 MB
  u16*   Vt   = (u16*)(ws + 101187584);    // 16.78 MB tiled [bh][kt32][dv][key]
  u16*   ObA  = (u16*)(ws + 117964800);    // 33.55 MB split-K partial A
  u16*   ObB  = (u16*)(ws + 151519232);    // 33.55 MB split-K partial B
  float* LA   = (float*)(ws + 0);          // aliases dead Xbf
  float* LB   = (float*)(ws + 524288);
  u16*   At   = Wqkv;                      // aliases dead Wqkv
  if (ws_size < 185073664) return;

  k_castall<<<24640, 256, 0, stream>>>((const float4*)x, (const float4*)wq,
                                       (const float4*)wk, (const float4*)wv,
                                       (const float4*)wo, (const float4*)rc,
                                       (const float4*)rsn,
                                       Xbf, Wqkv, Wob, (float4*)CSb);
  k_gemm_qkv<<<dim3(384), 512, 0, stream>>>(Xbf, Wqkv, (const float2*)CSb,
                                            Qb, Kb, Vt);
  k_flash<<<1024, 256, 0, stream>>>(Qb, Kb, Vt, ObA, ObB, LA, LB);
  k_combine<<<16384, 256, 0, stream>>>(ObA, ObB, LA, LB, lq1, lk1, lq2, lk2, subw, At);
  k_gemm_o<<<256, 512, 0, stream>>>(At, Wob, (float*)d_out);
}